// Round 3
// baseline (1853.913 us; speedup 1.0000x reference)
//
#include <hip/hip_runtime.h>
#include <math.h>

// Problem constants
constexpr int kBS   = 16;
constexpr int kL    = 50;
constexpr int kNB   = 64;
constexpr int kD    = 256;
constexpr int kNBLK = 65536;
constexpr int kMaxUsed = 51200;          // 16*50*64 worst-case unique ids
constexpr int kHChunk  = 25600;          // H-stage chunk rows

#define NEG_HUGE (-3.402823466e38f)

// ---------------- helpers ----------------
__device__ __forceinline__ unsigned f2sort(float f) {
    unsigned u = __float_as_uint(f);
    return (u & 0x80000000u) ? ~u : (u | 0x80000000u);   // monotone ascending map
}

__device__ __forceinline__ void bitonic_u64(unsigned long long* s, int i, int n) {
    for (int k = 2; k <= n; k <<= 1) {
        for (int j = k >> 1; j > 0; j >>= 1) {
            __syncthreads();
            int ixj = i ^ j;
            if (ixj > i) {
                unsigned long long x = s[i], y = s[ixj];
                bool sw = ((i & k) == 0) ? (x > y) : (x < y);
                if (sw) { s[i] = y; s[ixj] = x; }
            }
        }
    }
    __syncthreads();
}

// ---------------- dedup: flags -> exclusive scan -> compact ----------------
__global__ void k_clear(int* __restrict__ flags) {
    flags[blockIdx.x * 256 + threadIdx.x] = 0;
}
__global__ void k_mark(const int* __restrict__ ids, int* __restrict__ flags, int n) {
    int i = blockIdx.x * 256 + threadIdx.x;
    if (i < n) flags[ids[i]] = 1;
}
__global__ void k_scan_a(const int* __restrict__ flags, int* __restrict__ slots,
                         int* __restrict__ bsum) {
    int i = blockIdx.x * 256 + threadIdx.x;
    __shared__ int s[256];
    int v = flags[i];
    s[threadIdx.x] = v; __syncthreads();
    for (int o = 1; o < 256; o <<= 1) {
        int t2 = (threadIdx.x >= o) ? s[threadIdx.x - o] : 0;
        __syncthreads();
        s[threadIdx.x] += t2;
        __syncthreads();
    }
    slots[i] = s[threadIdx.x] - v;
    if (threadIdx.x == 255) bsum[blockIdx.x] = s[255];
}
__global__ void k_scan_b(int* __restrict__ bsum, int* __restrict__ mcount) {
    __shared__ int s[256];
    int v = bsum[threadIdx.x];
    s[threadIdx.x] = v; __syncthreads();
    for (int o = 1; o < 256; o <<= 1) {
        int t2 = (threadIdx.x >= o) ? s[threadIdx.x - o] : 0;
        __syncthreads();
        s[threadIdx.x] += t2;
        __syncthreads();
    }
    bsum[threadIdx.x] = s[threadIdx.x] - v;
    if (threadIdx.x == 255) *mcount = s[255];
}
__global__ void k_scan_c(const int* __restrict__ flags, int* __restrict__ slots,
                         const int* __restrict__ bsum, int* __restrict__ ulist) {
    int i = blockIdx.x * 256 + threadIdx.x;
    int slot = slots[i] + bsum[blockIdx.x];
    slots[i] = slot;
    if (flags[i]) ulist[slot] = i;
}

// ---------------- B-concat: Bcat[256][512] = [am_w1_hi | wk] ----------------
__global__ void k_bcat(const float* __restrict__ am_w1_hi, const float* __restrict__ wk,
                       float* __restrict__ Bcat) {
    int i = blockIdx.x * 256 + threadIdx.x;      // 0..131071
    int r = i >> 9, c = i & 511;
    Bcat[i] = (c < 256) ? am_w1_hi[r * 256 + c] : wk[r * 256 + (c - 256)];
}

// ---------------- f32 GEMM: BM=256, BN=128, BK=16, 16x8/thread ----------------
// Valid local rows r: r < mlim (mlim from mcount-moff or Mstatic).
// A row source: gather ? gather[arow_off+r] : (arow_off+r). C row: crow_off+r.
__global__ __launch_bounds__(256) void gemm256_f32(
    const float* __restrict__ A, int lda,
    const int* __restrict__ gather, int arow_off,
    const float* __restrict__ B, int ldb,
    float* __restrict__ C, int ldc, int crow_off,
    int Mstatic, const int* __restrict__ mcount, int moff,
    int K, const float* __restrict__ bias, int relu)
{
    int mlim = Mstatic;
    if (mcount) mlim = *mcount - moff;
    const int bm = blockIdx.x * 256;
    if (bm >= mlim) return;
    const int bn = blockIdx.y * 128;

    __shared__ float As[16][260];
    __shared__ float Bs[16][132];

    const int t  = threadIdx.x;
    const int tx = t & 15, ty = t >> 4;

    // A staging: 4 sweeps; row = bm + s*64 + (t>>2), kseg = (t&3)*4 (64B/row slices)
    const int rloc = t >> 2;
    const int kseg = (t & 3) * 4;
    long long asrc[4]; bool aok[4];
    #pragma unroll
    for (int s = 0; s < 4; ++s) {
        int r = bm + s * 64 + rloc;
        aok[s] = r < mlim;
        int g = 0;
        if (aok[s]) g = gather ? gather[arow_off + r] : (arow_off + r);
        asrc[s] = (long long)g * lda + kseg;
    }
    // B staging: 2 sweeps; k = h*8 + (t>>5), n = (t&31)*4
    const int kb = t >> 5;
    const int nb = (t & 31) * 4;

    float4 pa[4], pb[2];
    #pragma unroll
    for (int s = 0; s < 4; ++s)
        pa[s] = aok[s] ? *(const float4*)(A + asrc[s]) : make_float4(0.f, 0.f, 0.f, 0.f);
    #pragma unroll
    for (int h = 0; h < 2; ++h)
        pb[h] = *(const float4*)(B + (long long)(h * 8 + kb) * ldb + bn + nb);

    float acc[16][8];
    #pragma unroll
    for (int i = 0; i < 16; ++i)
        #pragma unroll
        for (int j = 0; j < 8; ++j) acc[i][j] = 0.f;

    const int nt = K / 16;
    for (int tI = 0; tI < nt; ++tI) {
        __syncthreads();
        #pragma unroll
        for (int s = 0; s < 4; ++s) {
            As[kseg + 0][s * 64 + rloc] = pa[s].x;
            As[kseg + 1][s * 64 + rloc] = pa[s].y;
            As[kseg + 2][s * 64 + rloc] = pa[s].z;
            As[kseg + 3][s * 64 + rloc] = pa[s].w;
        }
        #pragma unroll
        for (int h = 0; h < 2; ++h)
            *(float4*)&Bs[h * 8 + kb][nb] = pb[h];
        __syncthreads();
        if (tI + 1 < nt) {                       // issue next-tile loads (hide under compute)
            int k0 = (tI + 1) * 16;
            #pragma unroll
            for (int s = 0; s < 4; ++s)
                pa[s] = aok[s] ? *(const float4*)(A + asrc[s] + k0)
                               : make_float4(0.f, 0.f, 0.f, 0.f);
            #pragma unroll
            for (int h = 0; h < 2; ++h)
                pb[h] = *(const float4*)(B + (long long)(k0 + h * 8 + kb) * ldb + bn + nb);
        }
        #pragma unroll
        for (int k = 0; k < 16; ++k) {
            float a[16], b[8];
            *(float4*)&a[0]  = *(const float4*)&As[k][ty * 16];
            *(float4*)&a[4]  = *(const float4*)&As[k][ty * 16 + 4];
            *(float4*)&a[8]  = *(const float4*)&As[k][ty * 16 + 8];
            *(float4*)&a[12] = *(const float4*)&As[k][ty * 16 + 12];
            *(float4*)&b[0]  = *(const float4*)&Bs[k][tx * 8];
            *(float4*)&b[4]  = *(const float4*)&Bs[k][tx * 8 + 4];
            #pragma unroll
            for (int i = 0; i < 16; ++i)
                #pragma unroll
                for (int j = 0; j < 8; ++j)
                    acc[i][j] = fmaf(a[i], b[j], acc[i][j]);
        }
    }
    #pragma unroll
    for (int i = 0; i < 16; ++i) {
        int row = bm + ty * 16 + i;
        if (row >= mlim) continue;
        float* crow = C + (long long)(crow_off + row) * ldc + bn + tx * 8;
        #pragma unroll
        for (int j = 0; j < 8; ++j) {
            float v = acc[i][j];
            if (bias) v += bias[bn + tx * 8 + j];
            if (relu) v = fmaxf(v, 0.f);
            crow[j] = v;
        }
    }
}

// ---------------- in-place LayerNorm over rows of 256 ----------------
__global__ __launch_bounds__(256) void ln256_inplace(
    float* __restrict__ Y, const float* __restrict__ g, const float* __restrict__ b,
    int Mstatic, const int* __restrict__ mcount)
{
    int row = blockIdx.x;
    int mlim = mcount ? *mcount : Mstatic;
    if (row >= mlim) return;
    int d = threadIdx.x;
    float v = Y[(long long)row * 256 + d];
    __shared__ float red[256];
    red[d] = v; __syncthreads();
    for (int off = 128; off; off >>= 1) { if (d < off) red[d] += red[d + off]; __syncthreads(); }
    float mu = red[0] * (1.f / 256.f);
    __syncthreads();
    float dv = v - mu;
    red[d] = dv * dv; __syncthreads();
    for (int off = 128; off; off >>= 1) { if (d < off) red[d] += red[d + off]; __syncthreads(); }
    float var = red[0] * (1.f / 256.f);
    float out = g[d] * dv * (1.f / sqrtf(var + 1e-5f)) + b[d];
    Y[(long long)row * 256 + d] = out;
}

// ---------------- elementwise add ----------------
__global__ void add_vec(const float* __restrict__ a, const float* __restrict__ b,
                        float* __restrict__ c, int n)
{
    int i = blockIdx.x * 256 + threadIdx.x;
    if (i < n) c[i] = a[i] + b[i];
}

// ---------------- phase-1 scores: score = tanh(tvp + A[slot[id]]) . am_w2 ----------------
__global__ __launch_bounds__(256) void p1score(
    const float* __restrict__ tvp, const float* __restrict__ AK,
    const int* __restrict__ slots, const float* __restrict__ am_w2,
    const int* __restrict__ ids, float* __restrict__ scores)
{
    int bl = blockIdx.x;            // 0..799 == (b*50+l)
    int lane = threadIdx.x & 63;
    int wv   = threadIdx.x >> 6;    // 0..3
    float4 tv = *(const float4*)(tvp + (long long)bl * 256 + lane * 4);
    float4 w2 = *(const float4*)(am_w2 + lane * 4);
    for (int s = wv * 16; s < wv * 16 + 16; ++s) {
        int slot = slots[ids[bl * 64 + s]];
        float4 a = *(const float4*)(AK + (long long)slot * 512 + lane * 4);
        double p = (double)tanhf(tv.x + a.x) * w2.x
                 + (double)tanhf(tv.y + a.y) * w2.y
                 + (double)tanhf(tv.z + a.z) * w2.z
                 + (double)tanhf(tv.w + a.w) * w2.w;
        #pragma unroll
        for (int off = 32; off; off >>= 1) p += __shfl_down(p, off);
        if (lane == 0) scores[bl * 64 + s] = (float)p;
    }
}

// ---------------- phase-1 full sort (top-64 of 64, stable desc) ----------------
__global__ __launch_bounds__(64) void p1sort(
    const float* __restrict__ scores, const int* __restrict__ ids_in,
    const int* __restrict__ mk_in, int* __restrict__ sel_ids, int* __restrict__ sel_mk)
{
    int bl = blockIdx.x;
    int i = threadIdx.x;
    __shared__ unsigned long long s[64];
    float sc = scores[bl * 64 + i];
    int mk = mk_in[bl * 64 + i];
    float key = mk ? sc : NEG_HUGE;
    s[i] = ((unsigned long long)(~f2sort(key)) << 32) | (unsigned)i;
    bitonic_u64(s, i, 64);
    int src = (int)(unsigned)(s[i] & 0xffffffffull);
    sel_ids[bl * 64 + i] = ids_in[bl * 64 + src];
    sel_mk [bl * 64 + i] = mk_in [bl * 64 + src];
}

// ---------------- E table: tiled gather-GEMM over K-half of AK ----------------
__global__ __launch_bounds__(256) void etab2(
    const float* __restrict__ qw, const float* __restrict__ AK,
    const int* __restrict__ slots, const int* __restrict__ sel_ids,
    float* __restrict__ E)
{
    const int l = blockIdx.x;   // 0..49
    const int b = blockIdx.y;   // 0..15
    __shared__ float Ks[16][64];
    __shared__ float Qs[16][68];
    __shared__ int rowA[64];
    const int t  = threadIdx.x;
    const int tx = t & 15, ty = t >> 4;
    if (t < 64) rowA[t] = slots[sel_ids[(b * kL + l) * 64 + t]];
    __syncthreads();

    const int rA = t >> 2;          // 0..63
    const int kA = (t & 3) * 4;
    const float* aptr = AK + (long long)rowA[rA] * 512 + 256 + kA;
    const float* qbase = qw + ((long long)b * kL + 1) * 256;
    const bool tsok = rA < 49;

    double acc[4][4];
    #pragma unroll
    for (int i = 0; i < 4; ++i)
        #pragma unroll
        for (int j = 0; j < 4; ++j) acc[i][j] = 0.0;

    for (int k0 = 0; k0 < 256; k0 += 16) {
        float4 av = *(const float4*)(aptr + k0);
        float4 bv = make_float4(0.f, 0.f, 0.f, 0.f);
        if (tsok) bv = *(const float4*)(qbase + (long long)rA * 256 + k0 + kA);
        __syncthreads();
        Ks[kA + 0][rA] = av.x; Ks[kA + 1][rA] = av.y;
        Ks[kA + 2][rA] = av.z; Ks[kA + 3][rA] = av.w;
        Qs[kA + 0][rA] = bv.x; Qs[kA + 1][rA] = bv.y;
        Qs[kA + 2][rA] = bv.z; Qs[kA + 3][rA] = bv.w;
        __syncthreads();
        #pragma unroll
        for (int k = 0; k < 16; ++k) {
            float a[4], q[4];
            *(float4*)&a[0] = *(const float4*)&Ks[k][tx * 4];
            *(float4*)&q[0] = *(const float4*)&Qs[k][ty * 4];
            #pragma unroll
            for (int i = 0; i < 4; ++i)
                #pragma unroll
                for (int j = 0; j < 4; ++j)
                    acc[i][j] += (double)a[i] * (double)q[j];
        }
    }
    #pragma unroll
    for (int j = 0; j < 4; ++j) {
        int ts = ty * 4 + j;
        if (ts >= 49) continue;
        #pragma unroll
        for (int i = 0; i < 4; ++i) {
            int s = tx * 4 + i;
            E[((long long)b * 49 + ts) * 3200 + l * 64 + s] = (float)acc[i][j];
        }
    }
}

// ---------------- sequential memory recurrence (one block per batch) ----------------
__global__ __launch_bounds__(128) void recur(
    const float* __restrict__ E, const int* __restrict__ sel_ids,
    const int* __restrict__ sel_mk, const int* __restrict__ lengths,
    int* __restrict__ memf, float* __restrict__ dout_mem)
{
    int b = blockIdx.x;
    int t = threadIdx.x;
    __shared__ int cid[64], cmk[64], ccd[64];
    __shared__ int fid[128], fmk[128], fcd[128];
    __shared__ unsigned long long sk[128];
    if (t < 64) {
        cid[t] = sel_ids[(b * kL) * 64 + t];
        cmk[t] = sel_mk [(b * kL) * 64 + t];
        ccd[t] = t;
    }
    __syncthreads();
    int tlast = lengths[b] - 2;
    for (int ts = 0; ts <= tlast; ++ts) {
        int id, mk, cd;
        if (t < 64) { id = cid[t]; mk = cmk[t]; cd = ccd[t]; }
        else {
            int j = t - 64;
            id = sel_ids[(b * kL + ts + 1) * 64 + j];
            mk = sel_mk [(b * kL + ts + 1) * 64 + j];
            cd = (ts + 1) * 64 + j;
        }
        float key = mk ? E[((long long)b * 49 + ts) * 3200 + cd] : NEG_HUGE;
        fid[t] = id; fmk[t] = mk; fcd[t] = cd;
        sk[t] = ((unsigned long long)(~f2sort(key)) << 32) | (unsigned)t;
        bitonic_u64(sk, t, 128);
        if (t < 64) {
            int src = (int)(unsigned)(sk[t] & 0xffffffffull);
            cid[t] = fid[src]; cmk[t] = fmk[src]; ccd[t] = fcd[src];
        }
        __syncthreads();
    }
    if (t < 64) {
        int v = cid[t];
        memf[b * 64 + t] = v;
        dout_mem[b * 64 + t] = (float)v;
    }
}

// ---------------- final pooling + output head (mem rows gathered from T) ----------------
__global__ __launch_bounds__(256) void head_k(
    const float* __restrict__ tva, const int* __restrict__ lengths,
    const float* __restrict__ T, const int* __restrict__ slots,
    const int* __restrict__ memf, const float* __restrict__ out_w,
    const float* __restrict__ out_b, float* __restrict__ dout)
{
    int b = blockIdx.x, d = threadIdx.x;
    int len = lengths[b];
    float vf = NEG_HUGE;
    for (int l = 0; l < len; ++l) vf = fmaxf(vf, tva[((long long)b * kL + l) * 256 + d]);
    float mv = NEG_HUGE;
    for (int m = 0; m < 64; ++m) {
        int slot = slots[memf[b * 64 + m]];
        mv = fmaxf(mv, T[(long long)slot * 256 + d]);
    }
    double p0 = (double)vf * out_w[d * 2 + 0] + (double)mv * out_w[(256 + d) * 2 + 0];
    double p1 = (double)vf * out_w[d * 2 + 1] + (double)mv * out_w[(256 + d) * 2 + 1];
    __shared__ double r0[256], r1[256];
    r0[d] = p0; r1[d] = p1; __syncthreads();
    for (int off = 128; off; off >>= 1) {
        if (d < off) { r0[d] += r0[d + off]; r1[d] += r1[d + off]; }
        __syncthreads();
    }
    if (d == 0) {
        dout[b * 2 + 0] = (float)(r0[0] + out_b[0]);
        dout[b * 2 + 1] = (float)(r1[0] + out_b[1]);
    }
}

// ---------------- host orchestration ----------------
extern "C" void kernel_launch(void* const* d_in, const int* in_sizes, int n_in,
                              void* d_out, int out_size, void* d_ws, size_t ws_size,
                              hipStream_t stream)
{
    const float* v_all  = (const float*)d_in[0];
    const float* tva    = (const float*)d_in[1];
    const float* emb    = (const float*)d_in[2];
    const float* bt_w1  = (const float*)d_in[3];
    const float* bt_b1  = (const float*)d_in[4];
    const float* bt_w2  = (const float*)d_in[5];
    const float* bt_b2  = (const float*)d_in[6];
    const float* bt_g   = (const float*)d_in[7];
    const float* bt_bb  = (const float*)d_in[8];
    const float* wq     = (const float*)d_in[9];
    const float* wk     = (const float*)d_in[10];
    const float* am_w1  = (const float*)d_in[11];
    const float* am_b1  = (const float*)d_in[12];
    const float* am_w2  = (const float*)d_in[13];
    const float* out_w  = (const float*)d_in[14];
    const float* out_b  = (const float*)d_in[15];
    const int*   in_txt = (const int*)d_in[16];
    const int*   mk_txt = (const int*)d_in[17];
    const int*   lens   = (const int*)d_in[18];
    float* dout = (float*)d_out;

    // ---- workspace layout (floats); worst-case M = 51200 ----
    size_t off = 0;
    float* W = (float*)d_ws;
    auto take = [&](size_t n) { float* p = W + off; off += (n + 3) & ~(size_t)3; return p; };
    float* AK   = take((size_t)kMaxUsed * 512);          // [A | K] per used id
    float* Tt   = take((size_t)kMaxUsed * 256);          // blk_trans table (compacted)
    float* Hp   = take((size_t)kHChunk * 512);           // H chunk
    float* Ep   = take((size_t)16 * 49 * 3200);
    float* qrP  = take((size_t)800 * 256);
    float* tvpP = take((size_t)800 * 256);
    float* qwP  = take((size_t)800 * 256);
    float* Bcat = take((size_t)256 * 512);
    float* scP  = take((size_t)800 * 64);
    int*   selI = (int*)take((size_t)800 * 64);
    int*   selM = (int*)take((size_t)800 * 64);
    int*   flagsP = (int*)take(kNBLK);
    int*   slotsP = (int*)take(kNBLK);
    int*   ulist  = (int*)take(kNBLK);
    int*   bsum   = (int*)take(256);
    int*   mcount = (int*)take(16);
    int*   memfP  = (int*)take(1024);

    // 1) dedup pipeline
    k_clear<<<dim3(256), dim3(256), 0, stream>>>(flagsP);
    k_mark <<<dim3(200), dim3(256), 0, stream>>>(in_txt, flagsP, 51200);
    k_scan_a<<<dim3(256), dim3(256), 0, stream>>>(flagsP, slotsP, bsum);
    k_scan_b<<<dim3(1),   dim3(256), 0, stream>>>(bsum, mcount);
    k_scan_c<<<dim3(256), dim3(256), 0, stream>>>(flagsP, slotsP, bsum, ulist);
    k_bcat <<<dim3(512), dim3(256), 0, stream>>>(am_w1 + 256 * 256, wk, Bcat);

    // 2) query = tva + v_all ; tvp = tva@am_w1_lo + am_b1 ; qw = query@wq
    add_vec<<<dim3(800), dim3(256), 0, stream>>>(v_all, tva, qrP, 204800);
    gemm256_f32<<<dim3(4, 2), dim3(256), 0, stream>>>(
        tva, 256, nullptr, 0, am_w1, 256, tvpP, 256, 0, 800, nullptr, 0, 256, am_b1, 0);
    gemm256_f32<<<dim3(4, 2), dim3(256), 0, stream>>>(
        qrP, 256, nullptr, 0, wq, 256, qwP, 256, 0, 800, nullptr, 0, 256, nullptr, 0);

    // 3) table build over used ids: H -> T (chunked), then LN, then AK = T @ [A|K]
    for (int c = 0; c < 2; ++c) {
        gemm256_f32<<<dim3(kHChunk / 256, 4), dim3(256), 0, stream>>>(
            emb, 768, ulist, c * kHChunk, bt_w1, 512, Hp, 512, 0,
            0, mcount, c * kHChunk, 768, bt_b1, 1);
        gemm256_f32<<<dim3(kHChunk / 256, 2), dim3(256), 0, stream>>>(
            Hp, 512, nullptr, 0, bt_w2, 256, Tt, 256, c * kHChunk,
            0, mcount, c * kHChunk, 512, bt_b2, 0);
    }
    ln256_inplace<<<dim3(kMaxUsed), dim3(256), 0, stream>>>(Tt, bt_g, bt_bb, 0, mcount);
    gemm256_f32<<<dim3(kMaxUsed / 256, 4), dim3(256), 0, stream>>>(
        Tt, 256, nullptr, 0, Bcat, 512, AK, 512, 0, 0, mcount, 0, 256, nullptr, 0);

    // 4) phase-1 scores + stable full sort
    p1score<<<dim3(800), dim3(256), 0, stream>>>(tvpP, AK, slotsP, am_w2, in_txt, scP);
    p1sort<<<dim3(800), dim3(64), 0, stream>>>(scP, in_txt, mk_txt, selI, selM);

    // 5) E table
    etab2<<<dim3(50, 16), dim3(256), 0, stream>>>(qwP, AK, slotsP, selI, Ep);

    // 6) sequential recurrence -> memory_final (writes output 1)
    recur<<<dim3(16), dim3(128), 0, stream>>>(Ep, selI, selM, lens, memfP, dout + 32);

    // 7) pooling + output head (mem vectors gathered from T; writes output 0)
    head_k<<<dim3(16), dim3(256), 0, stream>>>(tva, lens, Tt, slotsP, memfP,
                                               out_w, out_b, dout);
}

// Round 4
// 1204.206 us; speedup vs baseline: 1.5395x; 1.5395x over previous
//
#include <hip/hip_runtime.h>
#include <math.h>

// Problem constants
constexpr int kBS   = 16;
constexpr int kL    = 50;
constexpr int kNB   = 64;
constexpr int kD    = 256;
constexpr int kNBLK = 65536;
constexpr int kMaxUsed = 51200;          // 16*50*64 worst-case unique ids
constexpr int kHChunk  = 25600;          // H-stage chunk rows

#define NEG_HUGE (-3.402823466e38f)

// ---------------- helpers ----------------
__device__ __forceinline__ unsigned f2sort(float f) {
    unsigned u = __float_as_uint(f);
    return (u & 0x80000000u) ? ~u : (u | 0x80000000u);   // monotone ascending map
}

__device__ __forceinline__ void bitonic_u64(unsigned long long* s, int i, int n) {
    for (int k = 2; k <= n; k <<= 1) {
        for (int j = k >> 1; j > 0; j >>= 1) {
            __syncthreads();
            int ixj = i ^ j;
            if (ixj > i) {
                unsigned long long x = s[i], y = s[ixj];
                bool sw = ((i & k) == 0) ? (x > y) : (x < y);
                if (sw) { s[i] = y; s[ixj] = x; }
            }
        }
    }
    __syncthreads();
}

// ---------------- dedup: flags -> exclusive scan -> compact ----------------
__global__ void k_clear(int* __restrict__ flags) {
    flags[blockIdx.x * 256 + threadIdx.x] = 0;
}
__global__ void k_mark(const int* __restrict__ ids, int* __restrict__ flags, int n) {
    int i = blockIdx.x * 256 + threadIdx.x;
    if (i < n) flags[ids[i]] = 1;
}
__global__ void k_scan_a(const int* __restrict__ flags, int* __restrict__ slots,
                         int* __restrict__ bsum) {
    int i = blockIdx.x * 256 + threadIdx.x;
    __shared__ int s[256];
    int v = flags[i];
    s[threadIdx.x] = v; __syncthreads();
    for (int o = 1; o < 256; o <<= 1) {
        int t2 = (threadIdx.x >= o) ? s[threadIdx.x - o] : 0;
        __syncthreads();
        s[threadIdx.x] += t2;
        __syncthreads();
    }
    slots[i] = s[threadIdx.x] - v;
    if (threadIdx.x == 255) bsum[blockIdx.x] = s[255];
}
__global__ void k_scan_b(int* __restrict__ bsum, int* __restrict__ mcount) {
    __shared__ int s[256];
    int v = bsum[threadIdx.x];
    s[threadIdx.x] = v; __syncthreads();
    for (int o = 1; o < 256; o <<= 1) {
        int t2 = (threadIdx.x >= o) ? s[threadIdx.x - o] : 0;
        __syncthreads();
        s[threadIdx.x] += t2;
        __syncthreads();
    }
    bsum[threadIdx.x] = s[threadIdx.x] - v;
    if (threadIdx.x == 255) *mcount = s[255];
}
__global__ void k_scan_c(const int* __restrict__ flags, int* __restrict__ slots,
                         const int* __restrict__ bsum, int* __restrict__ ulist) {
    int i = blockIdx.x * 256 + threadIdx.x;
    int slot = slots[i] + bsum[blockIdx.x];
    slots[i] = slot;
    if (flags[i]) ulist[slot] = i;
}

// ---------------- B-concat: Bcat[256][512] = [am_w1_hi | wk] ----------------
__global__ void k_bcat(const float* __restrict__ am_w1_hi, const float* __restrict__ wk,
                       float* __restrict__ Bcat) {
    int i = blockIdx.x * 256 + threadIdx.x;      // 0..131071
    int r = i >> 9, c = i & 511;
    Bcat[i] = (c < 256) ? am_w1_hi[r * 256 + c] : wk[r * 256 + (c - 256)];
}

// ---------------- f32 GEMM: BM=BN=128, BK=16, 8x8/thread, reg-prefetch ----------------
// A row r: gather ? gather[arow_off+r] : (arow_off+r). C row: crow_off+r.
// mlim = mcount ? *mcount - moff : Mstatic. Requires N%128==0, K%16==0.
__global__ __launch_bounds__(256) void gemm128_f32(
    const float* __restrict__ A, int lda,
    const int* __restrict__ gather, int arow_off,
    const float* __restrict__ B, int ldb,
    float* __restrict__ C, int ldc, int crow_off,
    int Mstatic, const int* __restrict__ mcount, int moff,
    int K, const float* __restrict__ bias, int relu)
{
    int mlim = Mstatic;
    if (mcount) mlim = *mcount - moff;
    const int bm = blockIdx.x * 128;
    if (bm >= mlim) return;
    const int bn = blockIdx.y * 128;

    __shared__ float As[16][128];
    __shared__ float Bs[16][132];
    const int t  = threadIdx.x;
    const int tx = t & 15, ty = t >> 4;

    const int mA   = t >> 1;          // 0..127
    const int kA   = (t & 1) * 8;     // 0 or 8
    const int rowA = bm + mA;
    const bool rowok = rowA < mlim;
    long long asrc = 0;
    if (rowok) {
        int g = gather ? gather[arow_off + rowA] : (arow_off + rowA);
        asrc = (long long)g * lda + kA;
    }
    const int kB = t >> 4;            // 0..15
    const int nB = (t & 15) * 8;      // 0..120
    const float* bptr = B + (long long)kB * ldb + bn + nB;

    float acc[8][8];
    #pragma unroll
    for (int i = 0; i < 8; ++i)
        #pragma unroll
        for (int j = 0; j < 8; ++j) acc[i][j] = 0.f;

    float4 a0 = make_float4(0.f,0.f,0.f,0.f), a1 = a0, b0, b1;
    if (rowok) {
        a0 = *(const float4*)(A + asrc);
        a1 = *(const float4*)(A + asrc + 4);
    }
    b0 = *(const float4*)(bptr);
    b1 = *(const float4*)(bptr + 4);

    const int nt = K / 16;
    for (int tI = 0; tI < nt; ++tI) {
        __syncthreads();
        As[kA + 0][mA] = a0.x; As[kA + 1][mA] = a0.y;
        As[kA + 2][mA] = a0.z; As[kA + 3][mA] = a0.w;
        As[kA + 4][mA] = a1.x; As[kA + 5][mA] = a1.y;
        As[kA + 6][mA] = a1.z; As[kA + 7][mA] = a1.w;
        *(float4*)&Bs[kB][nB]     = b0;
        *(float4*)&Bs[kB][nB + 4] = b1;
        __syncthreads();
        if (tI + 1 < nt) {                  // prefetch next tile under compute
            int k0 = (tI + 1) * 16;
            if (rowok) {
                a0 = *(const float4*)(A + asrc + k0);
                a1 = *(const float4*)(A + asrc + k0 + 4);
            }
            b0 = *(const float4*)(bptr + (long long)k0 * ldb);
            b1 = *(const float4*)(bptr + (long long)k0 * ldb + 4);
        }
        #pragma unroll
        for (int k = 0; k < 16; ++k) {
            float a[8], b[8];
            *(float4*)&a[0] = *(const float4*)&As[k][ty * 8];
            *(float4*)&a[4] = *(const float4*)&As[k][ty * 8 + 4];
            *(float4*)&b[0] = *(const float4*)&Bs[k][tx * 8];
            *(float4*)&b[4] = *(const float4*)&Bs[k][tx * 8 + 4];
            #pragma unroll
            for (int i = 0; i < 8; ++i)
                #pragma unroll
                for (int j = 0; j < 8; ++j)
                    acc[i][j] = fmaf(a[i], b[j], acc[i][j]);
        }
    }
    #pragma unroll
    for (int i = 0; i < 8; ++i) {
        int row = bm + ty * 8 + i;
        if (row >= mlim) continue;
        float* crow = C + (long long)(crow_off + row) * ldc + bn + tx * 8;
        #pragma unroll
        for (int j = 0; j < 8; ++j) {
            float v = acc[i][j];
            if (bias) v += bias[bn + tx * 8 + j];
            if (relu) v = fmaxf(v, 0.f);
            crow[j] = v;
        }
    }
}

// ---------------- in-place LayerNorm over rows of 256 ----------------
__global__ __launch_bounds__(256) void ln256_inplace(
    float* __restrict__ Y, const float* __restrict__ g, const float* __restrict__ b,
    int Mstatic, const int* __restrict__ mcount)
{
    int row = blockIdx.x;
    int mlim = mcount ? *mcount : Mstatic;
    if (row >= mlim) return;
    int d = threadIdx.x;
    float v = Y[(long long)row * 256 + d];
    __shared__ float red[256];
    red[d] = v; __syncthreads();
    for (int off = 128; off; off >>= 1) { if (d < off) red[d] += red[d + off]; __syncthreads(); }
    float mu = red[0] * (1.f / 256.f);
    __syncthreads();
    float dv = v - mu;
    red[d] = dv * dv; __syncthreads();
    for (int off = 128; off; off >>= 1) { if (d < off) red[d] += red[d + off]; __syncthreads(); }
    float var = red[0] * (1.f / 256.f);
    float out = g[d] * dv * (1.f / sqrtf(var + 1e-5f)) + b[d];
    Y[(long long)row * 256 + d] = out;
}

// ---------------- elementwise add ----------------
__global__ void add_vec(const float* __restrict__ a, const float* __restrict__ b,
                        float* __restrict__ c, int n)
{
    int i = blockIdx.x * 256 + threadIdx.x;
    if (i < n) c[i] = a[i] + b[i];
}

// ---------------- phase-1 scores: score = tanh(tvp + A[slot[id]]) . am_w2 ----------------
__global__ __launch_bounds__(256) void p1score(
    const float* __restrict__ tvp, const float* __restrict__ AK,
    const int* __restrict__ slots, const float* __restrict__ am_w2,
    const int* __restrict__ ids, float* __restrict__ scores)
{
    int bl = blockIdx.x;            // 0..799 == (b*50+l)
    int lane = threadIdx.x & 63;
    int wv   = threadIdx.x >> 6;    // 0..3
    float4 tv = *(const float4*)(tvp + (long long)bl * 256 + lane * 4);
    float4 w2 = *(const float4*)(am_w2 + lane * 4);
    for (int s = wv * 16; s < wv * 16 + 16; ++s) {
        int slot = slots[ids[bl * 64 + s]];
        float4 a = *(const float4*)(AK + (long long)slot * 512 + lane * 4);
        double p = (double)tanhf(tv.x + a.x) * w2.x
                 + (double)tanhf(tv.y + a.y) * w2.y
                 + (double)tanhf(tv.z + a.z) * w2.z
                 + (double)tanhf(tv.w + a.w) * w2.w;
        #pragma unroll
        for (int off = 32; off; off >>= 1) p += __shfl_down(p, off);
        if (lane == 0) scores[bl * 64 + s] = (float)p;
    }
}

// ---------------- phase-1 full sort (top-64 of 64, stable desc) ----------------
__global__ __launch_bounds__(64) void p1sort(
    const float* __restrict__ scores, const int* __restrict__ ids_in,
    const int* __restrict__ mk_in, int* __restrict__ sel_ids, int* __restrict__ sel_mk)
{
    int bl = blockIdx.x;
    int i = threadIdx.x;
    __shared__ unsigned long long s[64];
    float sc = scores[bl * 64 + i];
    int mk = mk_in[bl * 64 + i];
    float key = mk ? sc : NEG_HUGE;
    s[i] = ((unsigned long long)(~f2sort(key)) << 32) | (unsigned)i;
    bitonic_u64(s, i, 64);
    int src = (int)(unsigned)(s[i] & 0xffffffffull);
    sel_ids[bl * 64 + i] = ids_in[bl * 64 + src];
    sel_mk [bl * 64 + i] = mk_in [bl * 64 + src];
}

// ---------------- E table: tiled gather-GEMM over K-half of AK ----------------
__global__ __launch_bounds__(256) void etab2(
    const float* __restrict__ qw, const float* __restrict__ AK,
    const int* __restrict__ slots, const int* __restrict__ sel_ids,
    float* __restrict__ E)
{
    const int l = blockIdx.x;   // 0..49
    const int b = blockIdx.y;   // 0..15
    __shared__ float Ks[16][64];
    __shared__ float Qs[16][68];
    __shared__ int rowA[64];
    const int t  = threadIdx.x;
    const int tx = t & 15, ty = t >> 4;
    if (t < 64) rowA[t] = slots[sel_ids[(b * kL + l) * 64 + t]];
    __syncthreads();

    const int rA = t >> 2;          // 0..63
    const int kA = (t & 3) * 4;
    const float* aptr = AK + (long long)rowA[rA] * 512 + 256 + kA;
    const float* qbase = qw + ((long long)b * kL + 1) * 256;
    const bool tsok = rA < 49;

    double acc[4][4];
    #pragma unroll
    for (int i = 0; i < 4; ++i)
        #pragma unroll
        for (int j = 0; j < 4; ++j) acc[i][j] = 0.0;

    for (int k0 = 0; k0 < 256; k0 += 16) {
        float4 av = *(const float4*)(aptr + k0);
        float4 bv = make_float4(0.f, 0.f, 0.f, 0.f);
        if (tsok) bv = *(const float4*)(qbase + (long long)rA * 256 + k0 + kA);
        __syncthreads();
        Ks[kA + 0][rA] = av.x; Ks[kA + 1][rA] = av.y;
        Ks[kA + 2][rA] = av.z; Ks[kA + 3][rA] = av.w;
        Qs[kA + 0][rA] = bv.x; Qs[kA + 1][rA] = bv.y;
        Qs[kA + 2][rA] = bv.z; Qs[kA + 3][rA] = bv.w;
        __syncthreads();
        #pragma unroll
        for (int k = 0; k < 16; ++k) {
            float a[4], q[4];
            *(float4*)&a[0] = *(const float4*)&Ks[k][tx * 4];
            *(float4*)&q[0] = *(const float4*)&Qs[k][ty * 4];
            #pragma unroll
            for (int i = 0; i < 4; ++i)
                #pragma unroll
                for (int j = 0; j < 4; ++j)
                    acc[i][j] += (double)a[i] * (double)q[j];
        }
    }
    #pragma unroll
    for (int j = 0; j < 4; ++j) {
        int ts = ty * 4 + j;
        if (ts >= 49) continue;
        #pragma unroll
        for (int i = 0; i < 4; ++i) {
            int s = tx * 4 + i;
            E[((long long)b * 49 + ts) * 3200 + l * 64 + s] = (float)acc[i][j];
        }
    }
}

// ---------------- sequential memory recurrence (one block per batch) ----------------
__global__ __launch_bounds__(128) void recur(
    const float* __restrict__ E, const int* __restrict__ sel_ids,
    const int* __restrict__ sel_mk, const int* __restrict__ lengths,
    int* __restrict__ memf, float* __restrict__ dout_mem)
{
    int b = blockIdx.x;
    int t = threadIdx.x;
    __shared__ int cid[64], cmk[64], ccd[64];
    __shared__ int fid[128], fmk[128], fcd[128];
    __shared__ unsigned long long sk[128];
    if (t < 64) {
        cid[t] = sel_ids[(b * kL) * 64 + t];
        cmk[t] = sel_mk [(b * kL) * 64 + t];
        ccd[t] = t;
    }
    __syncthreads();
    int tlast = lengths[b] - 2;
    for (int ts = 0; ts <= tlast; ++ts) {
        int id, mk, cd;
        if (t < 64) { id = cid[t]; mk = cmk[t]; cd = ccd[t]; }
        else {
            int j = t - 64;
            id = sel_ids[(b * kL + ts + 1) * 64 + j];
            mk = sel_mk [(b * kL + ts + 1) * 64 + j];
            cd = (ts + 1) * 64 + j;
        }
        float key = mk ? E[((long long)b * 49 + ts) * 3200 + cd] : NEG_HUGE;
        fid[t] = id; fmk[t] = mk; fcd[t] = cd;
        sk[t] = ((unsigned long long)(~f2sort(key)) << 32) | (unsigned)t;
        bitonic_u64(sk, t, 128);
        if (t < 64) {
            int src = (int)(unsigned)(sk[t] & 0xffffffffull);
            cid[t] = fid[src]; cmk[t] = fmk[src]; ccd[t] = fcd[src];
        }
        __syncthreads();
    }
    if (t < 64) {
        int v = cid[t];
        memf[b * 64 + t] = v;
        dout_mem[b * 64 + t] = (float)v;
    }
}

// ---------------- final pooling + output head (mem rows gathered from T) ----------------
__global__ __launch_bounds__(256) void head_k(
    const float* __restrict__ tva, const int* __restrict__ lengths,
    const float* __restrict__ T, const int* __restrict__ slots,
    const int* __restrict__ memf, const float* __restrict__ out_w,
    const float* __restrict__ out_b, float* __restrict__ dout)
{
    int b = blockIdx.x, d = threadIdx.x;
    int len = lengths[b];
    float vf = NEG_HUGE;
    for (int l = 0; l < len; ++l) vf = fmaxf(vf, tva[((long long)b * kL + l) * 256 + d]);
    float mv = NEG_HUGE;
    for (int m = 0; m < 64; ++m) {
        int slot = slots[memf[b * 64 + m]];
        mv = fmaxf(mv, T[(long long)slot * 256 + d]);
    }
    double p0 = (double)vf * out_w[d * 2 + 0] + (double)mv * out_w[(256 + d) * 2 + 0];
    double p1 = (double)vf * out_w[d * 2 + 1] + (double)mv * out_w[(256 + d) * 2 + 1];
    __shared__ double r0[256], r1[256];
    r0[d] = p0; r1[d] = p1; __syncthreads();
    for (int off = 128; off; off >>= 1) {
        if (d < off) { r0[d] += r0[d + off]; r1[d] += r1[d + off]; }
        __syncthreads();
    }
    if (d == 0) {
        dout[b * 2 + 0] = (float)(r0[0] + out_b[0]);
        dout[b * 2 + 1] = (float)(r1[0] + out_b[1]);
    }
}

// ---------------- host orchestration ----------------
extern "C" void kernel_launch(void* const* d_in, const int* in_sizes, int n_in,
                              void* d_out, int out_size, void* d_ws, size_t ws_size,
                              hipStream_t stream)
{
    const float* v_all  = (const float*)d_in[0];
    const float* tva    = (const float*)d_in[1];
    const float* emb    = (const float*)d_in[2];
    const float* bt_w1  = (const float*)d_in[3];
    const float* bt_b1  = (const float*)d_in[4];
    const float* bt_w2  = (const float*)d_in[5];
    const float* bt_b2  = (const float*)d_in[6];
    const float* bt_g   = (const float*)d_in[7];
    const float* bt_bb  = (const float*)d_in[8];
    const float* wq     = (const float*)d_in[9];
    const float* wk     = (const float*)d_in[10];
    const float* am_w1  = (const float*)d_in[11];
    const float* am_b1  = (const float*)d_in[12];
    const float* am_w2  = (const float*)d_in[13];
    const float* out_w  = (const float*)d_in[14];
    const float* out_b  = (const float*)d_in[15];
    const int*   in_txt = (const int*)d_in[16];
    const int*   mk_txt = (const int*)d_in[17];
    const int*   lens   = (const int*)d_in[18];
    float* dout = (float*)d_out;

    // ---- workspace layout (floats); worst-case M = 51200 ----
    size_t off = 0;
    float* W = (float*)d_ws;
    auto take = [&](size_t n) { float* p = W + off; off += (n + 3) & ~(size_t)3; return p; };
    float* AK   = take((size_t)kMaxUsed * 512);          // [A | K] per used id
    float* Tt   = take((size_t)kMaxUsed * 256);          // blk_trans table (compacted)
    float* Hp   = take((size_t)kHChunk * 512);           // H chunk
    float* Ep   = take((size_t)16 * 49 * 3200);
    float* qrP  = take((size_t)800 * 256);
    float* tvpP = take((size_t)800 * 256);
    float* qwP  = take((size_t)800 * 256);
    float* Bcat = take((size_t)256 * 512);
    float* scP  = take((size_t)800 * 64);
    int*   selI = (int*)take((size_t)800 * 64);
    int*   selM = (int*)take((size_t)800 * 64);
    int*   flagsP = (int*)take(kNBLK);
    int*   slotsP = (int*)take(kNBLK);
    int*   ulist  = (int*)take(kNBLK);
    int*   bsum   = (int*)take(256);
    int*   mcount = (int*)take(16);
    int*   memfP  = (int*)take(1024);

    // 1) dedup pipeline
    k_clear<<<dim3(256), dim3(256), 0, stream>>>(flagsP);
    k_mark <<<dim3(200), dim3(256), 0, stream>>>(in_txt, flagsP, 51200);
    k_scan_a<<<dim3(256), dim3(256), 0, stream>>>(flagsP, slotsP, bsum);
    k_scan_b<<<dim3(1),   dim3(256), 0, stream>>>(bsum, mcount);
    k_scan_c<<<dim3(256), dim3(256), 0, stream>>>(flagsP, slotsP, bsum, ulist);
    k_bcat <<<dim3(512), dim3(256), 0, stream>>>(am_w1 + 256 * 256, wk, Bcat);

    // 2) query = tva + v_all ; tvp = tva@am_w1_lo + am_b1 ; qw = query@wq
    add_vec<<<dim3(800), dim3(256), 0, stream>>>(v_all, tva, qrP, 204800);
    gemm128_f32<<<dim3(7, 2), dim3(256), 0, stream>>>(
        tva, 256, nullptr, 0, am_w1, 256, tvpP, 256, 0, 800, nullptr, 0, 256, am_b1, 0);
    gemm128_f32<<<dim3(7, 2), dim3(256), 0, stream>>>(
        qrP, 256, nullptr, 0, wq, 256, qwP, 256, 0, 800, nullptr, 0, 256, nullptr, 0);

    // 3) table build over used ids: H -> T (chunked), then LN, then AK = T @ [A|K]
    for (int c = 0; c < 2; ++c) {
        gemm128_f32<<<dim3(kHChunk / 128, 4), dim3(256), 0, stream>>>(
            emb, 768, ulist, c * kHChunk, bt_w1, 512, Hp, 512, 0,
            0, mcount, c * kHChunk, 768, bt_b1, 1);
        gemm128_f32<<<dim3(kHChunk / 128, 2), dim3(256), 0, stream>>>(
            Hp, 512, nullptr, 0, bt_w2, 256, Tt, 256, c * kHChunk,
            0, mcount, c * kHChunk, 512, bt_b2, 0);
    }
    ln256_inplace<<<dim3(kMaxUsed), dim3(256), 0, stream>>>(Tt, bt_g, bt_bb, 0, mcount);
    gemm128_f32<<<dim3(kMaxUsed / 128, 4), dim3(256), 0, stream>>>(
        Tt, 256, nullptr, 0, Bcat, 512, AK, 512, 0, 0, mcount, 0, 256, nullptr, 0);

    // 4) phase-1 scores + stable full sort
    p1score<<<dim3(800), dim3(256), 0, stream>>>(tvpP, AK, slotsP, am_w2, in_txt, scP);
    p1sort<<<dim3(800), dim3(64), 0, stream>>>(scP, in_txt, mk_txt, selI, selM);

    // 5) E table
    etab2<<<dim3(50, 16), dim3(256), 0, stream>>>(qwP, AK, slotsP, selI, Ep);

    // 6) sequential recurrence -> memory_final (writes output 1)
    recur<<<dim3(16), dim3(128), 0, stream>>>(Ep, selI, selM, lens, memfP, dout + 32);

    // 7) pooling + output head (mem vectors gathered from T; writes output 0)
    head_k<<<dim3(16), dim3(256), 0, stream>>>(tva, lens, Tt, slotsP, memfP,
                                               out_w, out_b, dout);
}